// Round 1
// baseline (429.011 us; speedup 1.0000x reference)
//
#include <hip/hip_runtime.h>
#include <stdint.h>

#define B_ 4
#define N_ 16384
#define D_ 512
#define S_ 512

typedef __attribute__((ext_vector_type(8))) short bf16x8;
typedef __attribute__((ext_vector_type(4))) float f32x4;

__device__ __forceinline__ float bf2f(unsigned short u) {
  union { unsigned int i; float f; } v; v.i = ((unsigned int)u) << 16; return v.f;
}
__device__ __forceinline__ unsigned short f2bf(float f) {
  unsigned int x = __float_as_uint(f);
  return (unsigned short)((x + 0x7FFFu + ((x >> 16) & 1u)) >> 16);
}
__device__ __forceinline__ float ldf(const void* p, long i, bool f32) {
  return f32 ? ((const float*)p)[i] : bf2f(((const unsigned short*)p)[i]);
}
__device__ __forceinline__ void gl_lds16(void* lds_base, const void* g) {
  __builtin_amdgcn_global_load_lds(
      (const __attribute__((address_space(1))) unsigned int*)g,
      (__attribute__((address_space(3))) unsigned int*)lds_base,
      16, 0, 0);
}

__device__ __forceinline__ bool jx_is_i64(const int* jx32) { return jx32[N_ - 1] == 0; }
__device__ __forceinline__ int seg_id(const int* jx32, int n, bool i64) {
  return i64 ? jx32[2 * n] : jx32[n];
}

// Per-block dtype classify (true = x is f32); see round-2 notes.
__device__ __forceinline__ bool classify_f32(const unsigned short* x, int* cnt) {
  int c = 0;
#pragma unroll
  for (int i = 0; i < 8; i++) {
    unsigned short w = x[threadIdx.x * 8 + i];
    int e = (w >> 7) & 0xFF;
    if (e == 0 || (e >= 100 && e <= 140)) c++;
  }
  cnt[threadIdx.x] = c;
  __syncthreads();
  for (int s = 128; s > 0; s >>= 1) {
    if ((int)threadIdx.x < s) cnt[threadIdx.x] += cnt[threadIdx.x + s];
    __syncthreads();
  }
  bool f32 = cnt[0] < 1843;
  __syncthreads();
  return f32;
}

// ---------------------------------------------------------------------------
// prep_all: [0,16384) x -> xb bf16; [16384,19462) weights/biases;
// [19462,19465) segment bounds + publish flag for gather_out.
__global__ __launch_bounds__(256)
void prep_all(const void* __restrict__ x, const int* __restrict__ jx,
              const void* __restrict__ Wf, const void* __restrict__ bfv,
              const void* __restrict__ Wg, const void* __restrict__ bgv,
              const void* __restrict__ Wh, const void* __restrict__ bhv,
              unsigned short* __restrict__ xb, unsigned short* __restrict__ Wfg,
              unsigned short* __restrict__ biasfg, unsigned short* __restrict__ Whb,
              unsigned short* __restrict__ bhb, int* __restrict__ segst,
              int* __restrict__ flag) {
  const int blk = blockIdx.x, tid = threadIdx.x;
  __shared__ int cnt[256];
  const bool f32 = classify_f32((const unsigned short*)x, cnt);
  if (blk >= 19462) {  // bounds + flag
    if (blk == 19462 && tid == 0) flag[0] = f32 ? 1 : 0;
    int s = (blk - 19462) * 256 + tid;
    if (s > S_) return;
    bool i64 = jx_is_i64(jx);
    int lo = 0, hi = N_;
    while (lo < hi) {
      int mid = (lo + hi) >> 1;
      if (seg_id(jx, mid, i64) < s) lo = mid + 1; else hi = mid;
    }
    segst[s] = lo;
    return;
  }
  if (blk < 16384) {  // x -> bf16
    const size_t i0 = ((size_t)blk * 256 + tid) * 8;
    bf16x8 v;
    if (f32) {
      const float4* p = (const float4*)((const float*)x + i0);
      float4 a = p[0], b = p[1];
      v[0]=f2bf(a.x); v[1]=f2bf(a.y); v[2]=f2bf(a.z); v[3]=f2bf(a.w);
      v[4]=f2bf(b.x); v[5]=f2bf(b.y); v[6]=f2bf(b.z); v[7]=f2bf(b.w);
    } else {
      v = *(const bf16x8*)((const unsigned short*)x + i0);
    }
    *(bf16x8*)(xb + i0) = v;
  } else {  // weights / biases
    int idx = (blk - 16384) * 256 + tid;
    if (idx < 524288) {
      int e = idx >> 9, d = idx & 511;
      float v = (e < 512) ? ldf(Wf, (long)e * 512 + d, f32)
                          : ldf(Wg, (long)(e - 512) * 512 + d, f32);
      Wfg[idx] = f2bf(v);
    } else if (idx < 786432) {
      Whb[idx - 524288] = f2bf(ldf(Wh, idx - 524288, f32));
    } else if (idx < 787456) {
      int j = idx - 786432;
      biasfg[j] = f2bf(j < 512 ? ldf(bfv, j, f32) : ldf(bgv, j - 512, f32));
    } else if (idx < 787968) {
      bhb[idx - 787456] = f2bf(ldf(bhv, idx - 787456, f32));
    }
  }
}

// ---------------------------------------------------------------------------
// fg GEMM, round-4 rewrite: 256x256 tile, 8 waves (2Mx4N), BK=64, phase-split
// schedule (T3+T4 counted vmcnt), T2 XOR-swizzled LDS, T5 setprio.
//
// Why: previous 128x128 2-barrier loop measured 654 TF = the 2-phase
// structural ceiling (stage+vmcnt(0)+barrier dominates); T2/T5 are null
// there. This is the plain-HIP 8-phase-per-2-K-tiles template.
//
// LDS layout per K-tile buffer: [256 rows][8 slots of 16B]; slot s' holds
// global k-chunk s = s' ^ (row&7) (bank-conflict-free ds_read_b128:
// 16 lanes of a quarter-wave spread over all 32 banks, 2-way max).
// global_load_lds writes linearly (wave base + lane*16); the XOR is applied
// on the global SOURCE address (rule #21: both-sides-or-neither).
//
// Per K-tile t (buf c=t&1), 4 phases = 4 C-quadrants (qm,qn):
//   p0 (0,0): read A[qm0](8xb128)+B[qn0](4); stage B(t+1) cols{128,192}->c^1
//   p1 (0,1): read B[qn1](4), reuse A frags;  stage A(t+2) rows{0,128}->c
//   p2 (1,0): read A[qm1](8)+B[qn0](4);       stage B(t+1) cols{0,64}->c^1
//   p3 (1,1): read B[qn1](4), reuse A frags;  stage A(t+2) rows{64,192}->c
//             s_waitcnt vmcnt(2)   (vmcnt(0) for t>=NKT-2 tail drain)
// Stage targets only touch LDS rows whose reads completed in an earlier
// phase of the same iteration (A) or a different buffer (B). The per-wave
// vmcnt followed by s_barrier makes cross-wave staging completion sound.
#define NKT 8  // K = 512 = 8 tiles of 64

#define RD_A(QM)                                                              \
  _Pragma("unroll")                                                           \
  for (int rf = 0; rf < 4; ++rf) {                                            \
    const int arow = wm * 128 + (QM) * 64 + rf * 16 + l15;                    \
    af[rf][0] = *(const bf16x8*)((const char*)Ac + arow * 128 + s0);          \
    af[rf][1] = *(const bf16x8*)((const char*)Ac + arow * 128 + (s0 ^ 64));   \
  }

#define RD_B(QN)                                                              \
  _Pragma("unroll")                                                           \
  for (int cf = 0; cf < 2; ++cf) {                                            \
    const int brow = wn * 64 + (QN) * 32 + cf * 16 + l15;                     \
    bq[cf][0] = *(const bf16x8*)((const char*)Bc + brow * 128 + s0);          \
    bq[cf][1] = *(const bf16x8*)((const char*)Bc + brow * 128 + (s0 ^ 64));   \
  }

#define BAR_LG()                                                              \
  __builtin_amdgcn_s_barrier();                                               \
  asm volatile("s_waitcnt lgkmcnt(0)" ::: "memory");                          \
  __builtin_amdgcn_sched_barrier(0);

#define MFMA_Q(QM, QN)                                                        \
  __builtin_amdgcn_s_setprio(1);                                              \
  _Pragma("unroll")                                                           \
  for (int rf = 0; rf < 4; ++rf) {                                            \
    _Pragma("unroll")                                                         \
    for (int cf = 0; cf < 2; ++cf) {                                          \
      acc[(QM) * 4 + rf][(QN) * 2 + cf] =                                     \
          __builtin_amdgcn_mfma_f32_16x16x32_bf16(                            \
              af[rf][0], bq[cf][0], acc[(QM) * 4 + rf][(QN) * 2 + cf], 0, 0, 0); \
      acc[(QM) * 4 + rf][(QN) * 2 + cf] =                                     \
          __builtin_amdgcn_mfma_f32_16x16x32_bf16(                            \
              af[rf][1], bq[cf][1], acc[(QM) * 4 + rf][(QN) * 2 + cf], 0, 0, 0); \
    }                                                                         \
  }                                                                           \
  __builtin_amdgcn_s_setprio(0);

// One staging round: 512 threads x 16B = 8KB = 64 rows. LDS dest is linear
// (wave-uniform base + lane*16); global src column chunk is pre-XOR'd.
#define STG(LB, GP, GBASE, RB, KT)                                            \
  gl_lds16(&(LB)[((RB) + w8) * 64],                                           \
           (GP) + (size_t)((GBASE) + (RB) + w8 + lr) * 512 +                  \
               (size_t)(KT) * 64 + lsw)

__global__ __launch_bounds__(512, 2)
void gemm_fg(const unsigned short* __restrict__ A, const unsigned short* __restrict__ Bm,
             const unsigned short* __restrict__ bias,
             unsigned short* __restrict__ Cf, unsigned short* __restrict__ Cg) {
  __shared__ __align__(16) unsigned short Al[2][256 * 64];
  __shared__ __align__(16) unsigned short Bl[2][256 * 64];

  const int L = blockIdx.x;                 // 1024 blocks, %8==0 -> bijective
  const int xcd = L & 7, local = L >> 3;    // 4 consecutive 'local' share an
  const int tm = xcd * 32 + (local >> 2);   // A row-tile on one XCD's L2
  const int tn = local & 3;
  const int m0 = tm * 256, n0 = tn * 256;

  const int tid  = threadIdx.x;
  const int w    = tid >> 6;                // wave 0..7
  const int lane = tid & 63;
  const int wm   = w >> 2, wn = w & 3;      // 2 x 4 wave grid
  const int l15  = lane & 15, l4 = lane >> 4;
  // staging lane geometry (64-row round: row = RB + w*8 + lane>>3)
  const int w8  = w * 8;
  const int lr  = lane >> 3;
  const int lsw = ((lane & 7) ^ (lr & 7)) * 8;     // pre-swizzled k-chunk
  // read-side swizzle: byte slot for kh=0; kh=1 is s0^64
  const int s0  = ((l4 ^ (l15 & 7)) * 16);

  f32x4 acc[8][4];
#pragma unroll
  for (int i = 0; i < 8; i++)
#pragma unroll
    for (int j = 0; j < 4; j++) acc[i][j] = (f32x4){0.f, 0.f, 0.f, 0.f};
  bf16x8 af[4][2];   // current qm's A fragments [rf][kh]
  bf16x8 bq[2][2];   // current qn's B fragments [cf][kh]

  // prologue: A(0), B(0) -> buf0; A(1) -> buf1. B(1) is staged in-loop (t=0).
  STG(Al[0], A, m0, 0, 0);   STG(Al[0], A, m0, 128, 0);
  STG(Al[0], A, m0, 64, 0);  STG(Al[0], A, m0, 192, 0);
  STG(Bl[0], Bm, n0, 0, 0);  STG(Bl[0], Bm, n0, 64, 0);
  STG(Bl[0], Bm, n0, 128, 0); STG(Bl[0], Bm, n0, 192, 0);
  STG(Al[1], A, m0, 0, 1);   STG(Al[1], A, m0, 128, 1);
  STG(Al[1], A, m0, 64, 1);  STG(Al[1], A, m0, 192, 1);
  asm volatile("s_waitcnt vmcnt(4)" ::: "memory");  // A0+B0 done; A1 in flight
  __builtin_amdgcn_s_barrier();

#pragma unroll 2
  for (int t = 0; t < NKT; ++t) {
    const int c = t & 1;
    const unsigned short* Ac = Al[c];
    const unsigned short* Bc = Bl[c];
    unsigned short* An = Al[c];        // A(t+2) -> same buffer
    unsigned short* Bn = Bl[c ^ 1];    // B(t+1) -> other buffer
    const bool stB = (t + 1 < NKT);
    const bool stA = (t + 2 < NKT);

    // ---- phase 0: quadrant (0,0)
    RD_A(0); RD_B(0);
    if (stB) { STG(Bn, Bm, n0, 128, t + 1); STG(Bn, Bm, n0, 192, t + 1); }
    BAR_LG();
    MFMA_Q(0, 0);
    __builtin_amdgcn_s_barrier();

    // ---- phase 1: quadrant (0,1) — A frags reused
    RD_B(1);
    if (stA) { STG(An, A, m0, 0, t + 2); STG(An, A, m0, 128, t + 2); }
    BAR_LG();
    MFMA_Q(0, 1);
    __builtin_amdgcn_s_barrier();

    // ---- phase 2: quadrant (1,0)
    RD_A(1); RD_B(0);
    if (stB) { STG(Bn, Bm, n0, 0, t + 1); STG(Bn, Bm, n0, 64, t + 1); }
    BAR_LG();
    MFMA_Q(1, 0);
    __builtin_amdgcn_s_barrier();

    // ---- phase 3: quadrant (1,1) — A frags reused; counted vmcnt
    RD_B(1);
    if (stA) { STG(An, A, m0, 64, t + 2); STG(An, A, m0, 192, t + 2); }
    if (t >= NKT - 2) { asm volatile("s_waitcnt vmcnt(0)" ::: "memory"); }
    else              { asm volatile("s_waitcnt vmcnt(2)" ::: "memory"); }
    BAR_LG();
    MFMA_Q(1, 1);
    __builtin_amdgcn_s_barrier();
  }

  // epilogue: row = m0+wm*128+R*16+l4*4+r, col = n0+wn*64+C*16+l15
#pragma unroll
  for (int C = 0; C < 4; ++C) {
    const int col = n0 + wn * 64 + C * 16 + l15;
    const float bv = bf2f(bias[col]);
    unsigned short* base = (col < 512) ? Cf : Cg;
    const int cc = col & 511;
#pragma unroll
    for (int R = 0; R < 8; ++R) {
      const int rowb = m0 + wm * 128 + R * 16 + l4 * 4;
#pragma unroll
      for (int r = 0; r < 4; ++r)
        base[(size_t)(rowb + r) * 512 + cc] = f2bf(acc[R][C][r] + bv);
    }
  }
}

// ---------------------------------------------------------------------------
// Online segment softmax + weighted sum; 2 segments/block, 4 cols/thread,
// n-loop unrolled by 2 for load ILP. |g| < ~7 so no max subtraction.
__global__ __launch_bounds__(256)
void seg_softmax(const unsigned short* __restrict__ f, const unsigned short* __restrict__ g,
                 const int* __restrict__ segst, unsigned short* __restrict__ y) {
  const int s = blockIdx.x * 2 + (threadIdx.x >> 7);
  const int b = blockIdx.y;
  const int d0 = (threadIdx.x & 127) * 4;
  const int st = segst[s], en = segst[s + 1];
  float den0=0.f, den1=0.f, den2=0.f, den3=0.f;
  float y0=0.f, y1=0.f, y2=0.f, y3=0.f;
  int n = st;
  for (; n + 1 < en; n += 2) {
    const size_t offA = (size_t)(b * N_ + n) * 512 + d0;
    const size_t offB = offA + 512;
    const uint2 fpA = *(const uint2*)(f + offA);
    const uint2 gpA = *(const uint2*)(g + offA);
    const uint2 fpB = *(const uint2*)(f + offB);
    const uint2 gpB = *(const uint2*)(g + offB);
    {
      const float f0 = bf2f((unsigned short)fpA.x), f1 = bf2f((unsigned short)(fpA.x >> 16));
      const float f2 = bf2f((unsigned short)fpA.y), f3 = bf2f((unsigned short)(fpA.y >> 16));
      const float g0 = bf2f((unsigned short)gpA.x), g1 = bf2f((unsigned short)(gpA.x >> 16));
      const float g2 = bf2f((unsigned short)gpA.y), g3 = bf2f((unsigned short)(gpA.y >> 16));
      const float e0 = __expf(g0), e1 = __expf(g1), e2 = __expf(g2), e3 = __expf(g3);
      den0 += e0; den1 += e1; den2 += e2; den3 += e3;
      y0 += f0 * e0; y1 += f1 * e1; y2 += f2 * e2; y3 += f3 * e3;
    }
    {
      const float f0 = bf2f((unsigned short)fpB.x), f1 = bf2f((unsigned short)(fpB.x >> 16));
      const float f2 = bf2f((unsigned short)fpB.y), f3 = bf2f((unsigned short)(fpB.y >> 16));
      const float g0 = bf2f((unsigned short)gpB.x), g1 = bf2f((unsigned short)(gpB.x >> 16));
      const float g2 = bf2f((unsigned short)gpB.y), g3 = bf2f((unsigned short)(gpB.y >> 16));
      const float e0 = __expf(g0), e1 = __expf(g1), e2 = __expf(g2), e3 = __expf(g3);
      den0 += e0; den1 += e1; den2 += e2; den3 += e3;
      y0 += f0 * e0; y1 += f1 * e1; y2 += f2 * e2; y3 += f3 * e3;
    }
  }
  if (n < en) {
    const size_t off = (size_t)(b * N_ + n) * 512 + d0;
    const uint2 fp = *(const uint2*)(f + off);
    const uint2 gp = *(const uint2*)(g + off);
    const float f0 = bf2f((unsigned short)fp.x), f1 = bf2f((unsigned short)(fp.x >> 16));
    const float f2 = bf2f((unsigned short)fp.y), f3 = bf2f((unsigned short)(fp.y >> 16));
    const float g0 = bf2f((unsigned short)gp.x), g1 = bf2f((unsigned short)(gp.x >> 16));
    const float g2 = bf2f((unsigned short)gp.y), g3 = bf2f((unsigned short)(gp.y >> 16));
    const float e0 = __expf(g0), e1 = __expf(g1), e2 = __expf(g2), e3 = __expf(g3);
    den0 += e0; den1 += e1; den2 += e2; den3 += e3;
    y0 += f0 * e0; y1 += f1 * e1; y2 += f2 * e2; y3 += f3 * e3;
  }
  uint2 o;
  if (en > st) {
    o.x = (unsigned int)f2bf(y0 / den0) | ((unsigned int)f2bf(y1 / den1) << 16);
    o.y = (unsigned int)f2bf(y2 / den2) | ((unsigned int)f2bf(y3 / den3) << 16);
  } else { o.x = 0u; o.y = 0u; }
  *(uint2*)(y + (size_t)(b * S_ + s) * 512 + d0) = o;
}

// ---------------------------------------------------------------------------
// hy GEMM: hy[m,c] = sum_k y[m,k]*Whb[c,k] + bhb[c]; 64x64 tiles, 256 blocks.
__global__ __launch_bounds__(256)
void gemm_hy(const unsigned short* __restrict__ y, const unsigned short* __restrict__ Whb,
             const unsigned short* __restrict__ bhb, unsigned short* __restrict__ hy) {
  __shared__ __align__(16) unsigned short As[64 * 32];
  __shared__ __align__(16) unsigned short Bs[64 * 32];
  const int tid = threadIdx.x;
  const int w = tid >> 6, lane = tid & 63;
  const int l15 = lane & 15, l4 = lane >> 4;
  const int m0 = (blockIdx.x >> 3) * 64, c0 = (blockIdx.x & 7) * 64;
  const int srow = lane >> 2, scol = (lane & 3) * 8;

  f32x4 acc[4];
#pragma unroll
  for (int j = 0; j < 4; j++) acc[j] = (f32x4){0.f, 0.f, 0.f, 0.f};

  for (int kt = 0; kt < 512; kt += 32) {
    __syncthreads();
    gl_lds16(&As[(w * 16) * 32], y   + (size_t)(m0 + w * 16 + srow) * 512 + kt + scol);
    gl_lds16(&Bs[(w * 16) * 32], Whb + (size_t)(c0 + w * 16 + srow) * 512 + kt + scol);
    __syncthreads();
    bf16x8 a = *(const bf16x8*)&As[(w * 16 + l15) * 32 + l4 * 8];
#pragma unroll
    for (int j = 0; j < 4; j++) {
      bf16x8 bb = *(const bf16x8*)&Bs[(j * 16 + l15) * 32 + l4 * 8];
      acc[j] = __builtin_amdgcn_mfma_f32_16x16x32_bf16(a, bb, acc[j], 0, 0, 0);
    }
  }
#pragma unroll
  for (int j = 0; j < 4; j++) {
    const float bv = bf2f(bhb[c0 + j * 16 + l15]);
#pragma unroll
    for (int r = 0; r < 4; r++)
      hy[(size_t)(m0 + w * 16 + l4 * 4 + r) * 512 + c0 + j * 16 + l15] =
          f2bf(acc[j][r] + bv);
  }
}

// ---------------------------------------------------------------------------
// out[b,n,:] = hy[b*S + jx[n], :]; one wave per row, vectorized stores.
__global__ __launch_bounds__(256)
void gather_out(const unsigned short* __restrict__ hy, const int* __restrict__ jx,
                void* __restrict__ out, const int* __restrict__ flag) {
  const bool f32 = flag[0] != 0;
  const int gid  = blockIdx.x * 256 + threadIdx.x;
  const int wid  = gid >> 6;
  const int lane = gid & 63;
  const int b = wid >> 14;
  const int n = wid & (N_ - 1);
  const bool i64 = jx_is_i64(jx);
  const int s = seg_id(jx, n, i64);
  const bf16x8 v = *(const bf16x8*)(hy + (size_t)(b * S_ + s) * 512 + lane * 8);
  if (f32) {
    float* dst = (float*)out + (size_t)wid * 512 + lane * 8;
    float4 lo, hi;
    lo.x=bf2f((unsigned short)v[0]); lo.y=bf2f((unsigned short)v[1]);
    lo.z=bf2f((unsigned short)v[2]); lo.w=bf2f((unsigned short)v[3]);
    hi.x=bf2f((unsigned short)v[4]); hi.y=bf2f((unsigned short)v[5]);
    hi.z=bf2f((unsigned short)v[6]); hi.w=bf2f((unsigned short)v[7]);
    *(float4*)dst = lo;
    *(float4*)(dst + 4) = hi;
  } else {
    *(bf16x8*)((unsigned short*)out + (size_t)wid * 512 + lane * 8) = v;
  }
}

// ---------------------------------------------------------------------------
extern "C" void kernel_launch(void* const* d_in, const int* in_sizes, int n_in,
                              void* d_out, int out_size, void* d_ws, size_t ws_size,
                              hipStream_t stream) {
  const void* x  = d_in[0];
  const int* jx  = (const int*)d_in[1];
  const void* Wf = d_in[3];
  const void* bf = d_in[4];
  const void* Wg = d_in[5];
  const void* bg = d_in[6];
  const void* Wh = d_in[7];
  const void* bh = d_in[8];

  // EXACT R3-proven ws layout (ends at 72.4 MB; R5 showed 80.8 MB is OOB).
  char* ws = (char*)d_ws;
  int* flag              = (int*)(ws + 0);
  int* segst             = (int*)(ws + 4096);
  unsigned short* biasfg = (unsigned short*)(ws + 8192);
  unsigned short* bhb    = (unsigned short*)(ws + 16384);
  unsigned short* Wfg    = (unsigned short*)(ws + 32768);      // 1 MB
  unsigned short* Whb    = (unsigned short*)(ws + 1081344);    // 0.5 MB
  unsigned short* y_ws   = (unsigned short*)(ws + 1605632);    // 2 MB
  unsigned short* hy_ws  = (unsigned short*)(ws + 3702784);    // 2 MB
  unsigned short* xb     = (unsigned short*)(ws + 8388608);    // 64 MB bf16 x
  // f/g (2 x 64 MB bf16) live in d_out (128 MB f32); dead before gather.
  unsigned short* fbuf   = (unsigned short*)d_out;
  unsigned short* gbuf   = (unsigned short*)d_out + (size_t)B_ * N_ * D_;

  prep_all<<<19465, 256, 0, stream>>>(x, jx, Wf, bf, Wg, bg, Wh, bh,
                                      xb, Wfg, biasfg, Whb, bhb, segst, flag);
  gemm_fg<<<1024, 512, 0, stream>>>(xb, Wfg, biasfg, fbuf, gbuf);
  seg_softmax<<<dim3(256, B_), 256, 0, stream>>>(fbuf, gbuf, segst, y_ws);
  gemm_hy<<<256, 256, 0, stream>>>(y_ws, Whb, bhb, hy_ws);
  gather_out<<<16384, 256, 0, stream>>>(hy_ws, jx, d_out, flag);
}

// Round 2
// 425.499 us; speedup vs baseline: 1.0083x; 1.0083x over previous
//
#include <hip/hip_runtime.h>
#include <stdint.h>

#define B_ 4
#define N_ 16384
#define D_ 512
#define S_ 512

typedef __attribute__((ext_vector_type(8))) short bf16x8;
typedef __attribute__((ext_vector_type(4))) float f32x4;

__device__ __forceinline__ float bf2f(unsigned short u) {
  union { unsigned int i; float f; } v; v.i = ((unsigned int)u) << 16; return v.f;
}
__device__ __forceinline__ unsigned short f2bf(float f) {
  unsigned int x = __float_as_uint(f);
  return (unsigned short)((x + 0x7FFFu + ((x >> 16) & 1u)) >> 16);
}
__device__ __forceinline__ float ldf(const void* p, long i, bool f32) {
  return f32 ? ((const float*)p)[i] : bf2f(((const unsigned short*)p)[i]);
}
__device__ __forceinline__ void gl_lds16(void* lds_base, const void* g) {
  __builtin_amdgcn_global_load_lds(
      (const __attribute__((address_space(1))) unsigned int*)g,
      (__attribute__((address_space(3))) unsigned int*)lds_base,
      16, 0, 0);
}

__device__ __forceinline__ bool jx_is_i64(const int* jx32) { return jx32[N_ - 1] == 0; }
__device__ __forceinline__ int seg_id(const int* jx32, int n, bool i64) {
  return i64 ? jx32[2 * n] : jx32[n];
}

// Per-block dtype classify (true = x is f32); see round-2 notes.
__device__ __forceinline__ bool classify_f32(const unsigned short* x, int* cnt) {
  int c = 0;
#pragma unroll
  for (int i = 0; i < 8; i++) {
    unsigned short w = x[threadIdx.x * 8 + i];
    int e = (w >> 7) & 0xFF;
    if (e == 0 || (e >= 100 && e <= 140)) c++;
  }
  cnt[threadIdx.x] = c;
  __syncthreads();
  for (int s = 128; s > 0; s >>= 1) {
    if ((int)threadIdx.x < s) cnt[threadIdx.x] += cnt[threadIdx.x + s];
    __syncthreads();
  }
  bool f32 = cnt[0] < 1843;
  __syncthreads();
  return f32;
}

// ---------------------------------------------------------------------------
// prep_all (R5 slim): x-pass ELIMINATED (gemm_fg converts during staging).
// [0,3078) weights/biases; [3078,3081) segment bounds + publish flag.
__global__ __launch_bounds__(256)
void prep_all(const void* __restrict__ x, const int* __restrict__ jx,
              const void* __restrict__ Wf, const void* __restrict__ bfv,
              const void* __restrict__ Wg, const void* __restrict__ bgv,
              const void* __restrict__ Wh, const void* __restrict__ bhv,
              unsigned short* __restrict__ Wfg, unsigned short* __restrict__ biasfg,
              unsigned short* __restrict__ Whb, unsigned short* __restrict__ bhb,
              int* __restrict__ segst, int* __restrict__ flag) {
  const int blk = blockIdx.x, tid = threadIdx.x;
  __shared__ int cnt[256];
  const bool f32 = classify_f32((const unsigned short*)x, cnt);
  if (blk >= 3078) {  // bounds + flag
    if (blk == 3078 && tid == 0) flag[0] = f32 ? 1 : 0;
    int s = (blk - 3078) * 256 + tid;
    if (s > S_) return;
    bool i64 = jx_is_i64(jx);
    int lo = 0, hi = N_;
    while (lo < hi) {
      int mid = (lo + hi) >> 1;
      if (seg_id(jx, mid, i64) < s) lo = mid + 1; else hi = mid;
    }
    segst[s] = lo;
    return;
  }
  int idx = blk * 256 + tid;
  if (idx < 524288) {
    int e = idx >> 9, d = idx & 511;
    float v = (e < 512) ? ldf(Wf, (long)e * 512 + d, f32)
                        : ldf(Wg, (long)(e - 512) * 512 + d, f32);
    Wfg[idx] = f2bf(v);
  } else if (idx < 786432) {
    Whb[idx - 524288] = f2bf(ldf(Wh, idx - 524288, f32));
  } else if (idx < 787456) {
    int j = idx - 786432;
    biasfg[j] = f2bf(j < 512 ? ldf(bfv, j, f32) : ldf(bgv, j - 512, f32));
  } else if (idx < 787968) {
    bhb[idx - 787456] = f2bf(ldf(bhv, idx - 787456, f32));
  }
}

// ---------------------------------------------------------------------------
// fg GEMM (R3-proven 2-phase structure, 654 TF): C[m,e]=sum_k A[m,k]*Wfg[e,k]
// + bias[e]; 128x128 tile, BK=32, 4 waves 2x2, 4x4 mfma 16x16x32, XCD swizzle.
// R6 change: A is read DIRECTLY from x. f32 path reg-stages with inline
// f2bf (identical rounding to the old prep_all pass -> bit-identical output);
// bf16 path uses global_load_lds as before. Eliminates the 192 MB xb
// round-trip (prep read 128 + write 64, gemm re-read 64).
#define BK 32

__global__ __launch_bounds__(256, 2)
void gemm_fg(const void* __restrict__ X, const int* __restrict__ flag,
             const unsigned short* __restrict__ Bm,
             const unsigned short* __restrict__ bias,
             unsigned short* __restrict__ Cf, unsigned short* __restrict__ Cg) {
  __shared__ __align__(16) unsigned short As[128 * BK];
  __shared__ __align__(16) unsigned short Bs[128 * BK];
  const bool xf32 = flag[0] != 0;
  const int L = blockIdx.x;
  const int xcd = L & 7, local = L >> 3;
  const int tm = xcd * 64 + local / 8;     // tilesM=512 -> 64 per XCD
  const int tn = local % 8;
  const int m0 = tm * 128, n0 = tn * 128;

  const int tid  = threadIdx.x;
  const int w    = tid >> 6;
  const int lane = tid & 63;
  const int wm   = w >> 1, wn = w & 1;
  const int l15  = lane & 15, l4 = lane >> 4;
  const int srow = lane >> 2;
  const int scol = (lane & 3) * 8;

  f32x4 acc[4][4];
#pragma unroll
  for (int i = 0; i < 4; i++)
#pragma unroll
    for (int j = 0; j < 4; j++) acc[i][j] = (f32x4){0.f, 0.f, 0.f, 0.f};

  for (int kt = 0; kt < 512; kt += BK) {
    __syncthreads();
    if (xf32) {
      // reg-stage A from f32: 4 rounds x (16B load, cvt, 8B ds_write).
      const float* xf = (const float*)X;
#pragma unroll
      for (int q = 0; q < 4; q++) {
        const int e0 = (q * 256 + tid) * 4;
        const int r = e0 >> 5, k = e0 & 31;
        const float4 v = *(const float4*)(xf + (size_t)(m0 + r) * 512 + kt + k);
        ushort4 h;
        h.x = f2bf(v.x); h.y = f2bf(v.y); h.z = f2bf(v.z); h.w = f2bf(v.w);
        *(ushort4*)&As[r * BK + k] = h;
      }
    } else {
      const unsigned short* xh = (const unsigned short*)X;
#pragma unroll
      for (int r = 0; r < 2; r++) {
        const int rb = (r * 4 + w) * 16;
        gl_lds16(&As[rb * BK], xh + (size_t)(m0 + rb + srow) * 512 + kt + scol);
      }
    }
#pragma unroll
    for (int r = 0; r < 2; r++) {
      const int rb = (r * 4 + w) * 16;
      gl_lds16(&Bs[rb * BK], Bm + (size_t)(n0 + rb + srow) * 512 + kt + scol);
    }
    __syncthreads();

    bf16x8 a[4], bb[4];
#pragma unroll
    for (int i = 0; i < 4; i++)
      a[i] = *(const bf16x8*)&As[(wm * 64 + i * 16 + l15) * BK + l4 * 8];
#pragma unroll
    for (int j = 0; j < 4; j++)
      bb[j] = *(const bf16x8*)&Bs[(wn * 64 + j * 16 + l15) * BK + l4 * 8];
#pragma unroll
    for (int i = 0; i < 4; i++)
#pragma unroll
      for (int j = 0; j < 4; j++)
        acc[i][j] = __builtin_amdgcn_mfma_f32_16x16x32_bf16(a[i], bb[j], acc[i][j], 0, 0, 0);
  }

  // epilogue: C/D layout col=lane&15, row=(lane>>4)*4+r; split f (col<512) / g
#pragma unroll
  for (int j = 0; j < 4; j++) {
    const int col = n0 + wn * 64 + j * 16 + l15;
    const float bv = bf2f(bias[col]);
    unsigned short* base = (col < 512) ? Cf : Cg;
    const int cc = col & 511;
#pragma unroll
    for (int i = 0; i < 4; i++) {
      const int rowb = m0 + wm * 64 + i * 16 + l4 * 4;
#pragma unroll
      for (int r = 0; r < 4; r++)
        base[(size_t)(rowb + r) * 512 + cc] = f2bf(acc[i][j][r] + bv);
    }
  }
}

// ---------------------------------------------------------------------------
// Online segment softmax + weighted sum; 2 segments/block, 4 cols/thread,
// n-loop unrolled by 2 for load ILP. |g| < ~7 so no max subtraction.
__global__ __launch_bounds__(256)
void seg_softmax(const unsigned short* __restrict__ f, const unsigned short* __restrict__ g,
                 const int* __restrict__ segst, unsigned short* __restrict__ y) {
  const int s = blockIdx.x * 2 + (threadIdx.x >> 7);
  const int b = blockIdx.y;
  const int d0 = (threadIdx.x & 127) * 4;
  const int st = segst[s], en = segst[s + 1];
  float den0=0.f, den1=0.f, den2=0.f, den3=0.f;
  float y0=0.f, y1=0.f, y2=0.f, y3=0.f;
  int n = st;
  for (; n + 1 < en; n += 2) {
    const size_t offA = (size_t)(b * N_ + n) * 512 + d0;
    const size_t offB = offA + 512;
    const uint2 fpA = *(const uint2*)(f + offA);
    const uint2 gpA = *(const uint2*)(g + offA);
    const uint2 fpB = *(const uint2*)(f + offB);
    const uint2 gpB = *(const uint2*)(g + offB);
    {
      const float f0 = bf2f((unsigned short)fpA.x), f1 = bf2f((unsigned short)(fpA.x >> 16));
      const float f2 = bf2f((unsigned short)fpA.y), f3 = bf2f((unsigned short)(fpA.y >> 16));
      const float g0 = bf2f((unsigned short)gpA.x), g1 = bf2f((unsigned short)(gpA.x >> 16));
      const float g2 = bf2f((unsigned short)gpA.y), g3 = bf2f((unsigned short)(gpA.y >> 16));
      const float e0 = __expf(g0), e1 = __expf(g1), e2 = __expf(g2), e3 = __expf(g3);
      den0 += e0; den1 += e1; den2 += e2; den3 += e3;
      y0 += f0 * e0; y1 += f1 * e1; y2 += f2 * e2; y3 += f3 * e3;
    }
    {
      const float f0 = bf2f((unsigned short)fpB.x), f1 = bf2f((unsigned short)(fpB.x >> 16));
      const float f2 = bf2f((unsigned short)fpB.y), f3 = bf2f((unsigned short)(fpB.y >> 16));
      const float g0 = bf2f((unsigned short)gpB.x), g1 = bf2f((unsigned short)(gpB.x >> 16));
      const float g2 = bf2f((unsigned short)gpB.y), g3 = bf2f((unsigned short)(gpB.y >> 16));
      const float e0 = __expf(g0), e1 = __expf(g1), e2 = __expf(g2), e3 = __expf(g3);
      den0 += e0; den1 += e1; den2 += e2; den3 += e3;
      y0 += f0 * e0; y1 += f1 * e1; y2 += f2 * e2; y3 += f3 * e3;
    }
  }
  if (n < en) {
    const size_t off = (size_t)(b * N_ + n) * 512 + d0;
    const uint2 fp = *(const uint2*)(f + off);
    const uint2 gp = *(const uint2*)(g + off);
    const float f0 = bf2f((unsigned short)fp.x), f1 = bf2f((unsigned short)(fp.x >> 16));
    const float f2 = bf2f((unsigned short)fp.y), f3 = bf2f((unsigned short)(fp.y >> 16));
    const float g0 = bf2f((unsigned short)gp.x), g1 = bf2f((unsigned short)(gp.x >> 16));
    const float g2 = bf2f((unsigned short)gp.y), g3 = bf2f((unsigned short)(gp.y >> 16));
    const float e0 = __expf(g0), e1 = __expf(g1), e2 = __expf(g2), e3 = __expf(g3);
    den0 += e0; den1 += e1; den2 += e2; den3 += e3;
    y0 += f0 * e0; y1 += f1 * e1; y2 += f2 * e2; y3 += f3 * e3;
  }
  uint2 o;
  if (en > st) {
    o.x = (unsigned int)f2bf(y0 / den0) | ((unsigned int)f2bf(y1 / den1) << 16);
    o.y = (unsigned int)f2bf(y2 / den2) | ((unsigned int)f2bf(y3 / den3) << 16);
  } else { o.x = 0u; o.y = 0u; }
  *(uint2*)(y + (size_t)(b * S_ + s) * 512 + d0) = o;
}

// ---------------------------------------------------------------------------
// hy GEMM: hy[m,c] = sum_k y[m,k]*Whb[c,k] + bhb[c]; 64x64 tiles, 256 blocks.
__global__ __launch_bounds__(256)
void gemm_hy(const unsigned short* __restrict__ y, const unsigned short* __restrict__ Whb,
             const unsigned short* __restrict__ bhb, unsigned short* __restrict__ hy) {
  __shared__ __align__(16) unsigned short As[64 * 32];
  __shared__ __align__(16) unsigned short Bs[64 * 32];
  const int tid = threadIdx.x;
  const int w = tid >> 6, lane = tid & 63;
  const int l15 = lane & 15, l4 = lane >> 4;
  const int m0 = (blockIdx.x >> 3) * 64, c0 = (blockIdx.x & 7) * 64;
  const int srow = lane >> 2, scol = (lane & 3) * 8;

  f32x4 acc[4];
#pragma unroll
  for (int j = 0; j < 4; j++) acc[j] = (f32x4){0.f, 0.f, 0.f, 0.f};

  for (int kt = 0; kt < 512; kt += 32) {
    __syncthreads();
    gl_lds16(&As[(w * 16) * 32], y   + (size_t)(m0 + w * 16 + srow) * 512 + kt + scol);
    gl_lds16(&Bs[(w * 16) * 32], Whb + (size_t)(c0 + w * 16 + srow) * 512 + kt + scol);
    __syncthreads();
    bf16x8 a = *(const bf16x8*)&As[(w * 16 + l15) * 32 + l4 * 8];
#pragma unroll
    for (int j = 0; j < 4; j++) {
      bf16x8 bb = *(const bf16x8*)&Bs[(j * 16 + l15) * 32 + l4 * 8];
      acc[j] = __builtin_amdgcn_mfma_f32_16x16x32_bf16(a, bb, acc[j], 0, 0, 0);
    }
  }
#pragma unroll
  for (int j = 0; j < 4; j++) {
    const float bv = bf2f(bhb[c0 + j * 16 + l15]);
#pragma unroll
    for (int r = 0; r < 4; r++)
      hy[(size_t)(m0 + w * 16 + l4 * 4 + r) * 512 + c0 + j * 16 + l15] =
          f2bf(acc[j][r] + bv);
  }
}

// ---------------------------------------------------------------------------
// out[b,n,:] = hy[b*S + jx[n], :]; one wave per row, vectorized stores.
__global__ __launch_bounds__(256)
void gather_out(const unsigned short* __restrict__ hy, const int* __restrict__ jx,
                void* __restrict__ out, const int* __restrict__ flag) {
  const bool f32 = flag[0] != 0;
  const int gid  = blockIdx.x * 256 + threadIdx.x;
  const int wid  = gid >> 6;
  const int lane = gid & 63;
  const int b = wid >> 14;
  const int n = wid & (N_ - 1);
  const bool i64 = jx_is_i64(jx);
  const int s = seg_id(jx, n, i64);
  const bf16x8 v = *(const bf16x8*)(hy + (size_t)(b * S_ + s) * 512 + lane * 8);
  if (f32) {
    float* dst = (float*)out + (size_t)wid * 512 + lane * 8;
    float4 lo, hi;
    lo.x=bf2f((unsigned short)v[0]); lo.y=bf2f((unsigned short)v[1]);
    lo.z=bf2f((unsigned short)v[2]); lo.w=bf2f((unsigned short)v[3]);
    hi.x=bf2f((unsigned short)v[4]); hi.y=bf2f((unsigned short)v[5]);
    hi.z=bf2f((unsigned short)v[6]); hi.w=bf2f((unsigned short)v[7]);
    *(float4*)dst = lo;
    *(float4*)(dst + 4) = hi;
  } else {
    *(bf16x8*)((unsigned short*)out + (size_t)wid * 512 + lane * 8) = v;
  }
}

// ---------------------------------------------------------------------------
extern "C" void kernel_launch(void* const* d_in, const int* in_sizes, int n_in,
                              void* d_out, int out_size, void* d_ws, size_t ws_size,
                              hipStream_t stream) {
  const void* x  = d_in[0];
  const int* jx  = (const int*)d_in[1];
  const void* Wf = d_in[3];
  const void* bf = d_in[4];
  const void* Wg = d_in[5];
  const void* bg = d_in[6];
  const void* Wh = d_in[7];
  const void* bh = d_in[8];

  // EXACT R3-proven ws layout (ends at 72.4 MB; R5 showed 80.8 MB is OOB).
  // xb region now unused (gemm_fg reads x directly) but layout kept.
  char* ws = (char*)d_ws;
  int* flag              = (int*)(ws + 0);
  int* segst             = (int*)(ws + 4096);
  unsigned short* biasfg = (unsigned short*)(ws + 8192);
  unsigned short* bhb    = (unsigned short*)(ws + 16384);
  unsigned short* Wfg    = (unsigned short*)(ws + 32768);      // 1 MB
  unsigned short* Whb    = (unsigned short*)(ws + 1081344);    // 0.5 MB
  unsigned short* y_ws   = (unsigned short*)(ws + 1605632);    // 2 MB
  unsigned short* hy_ws  = (unsigned short*)(ws + 3702784);    // 2 MB
  // f/g (2 x 64 MB bf16) live in d_out (128 MB f32); dead before gather.
  unsigned short* fbuf   = (unsigned short*)d_out;
  unsigned short* gbuf   = (unsigned short*)d_out + (size_t)B_ * N_ * D_;

  prep_all<<<3081, 256, 0, stream>>>(x, jx, Wf, bf, Wg, bg, Wh, bh,
                                     Wfg, biasfg, Whb, bhb, segst, flag);
  gemm_fg<<<4096, 256, 0, stream>>>(x, flag, Wfg, biasfg, fbuf, gbuf);
  seg_softmax<<<dim3(256, B_), 256, 0, stream>>>(fbuf, gbuf, segst, y_ws);
  gemm_hy<<<256, 256, 0, stream>>>(y_ws, Whb, bhb, hy_ws);
  gather_out<<<16384, 256, 0, stream>>>(hy_ws, jx, d_out, flag);
}

// Round 3
// 405.679 us; speedup vs baseline: 1.0575x; 1.0489x over previous
//
#include <hip/hip_runtime.h>
#include <stdint.h>

#define B_ 4
#define N_ 16384
#define D_ 512
#define S_ 512

typedef __attribute__((ext_vector_type(8))) short bf16x8;
typedef __attribute__((ext_vector_type(4))) float f32x4;

__device__ __forceinline__ float bf2f(unsigned short u) {
  union { unsigned int i; float f; } v; v.i = ((unsigned int)u) << 16; return v.f;
}
__device__ __forceinline__ unsigned short f2bf(float f) {
  unsigned int x = __float_as_uint(f);
  return (unsigned short)((x + 0x7FFFu + ((x >> 16) & 1u)) >> 16);
}
__device__ __forceinline__ float ldf(const void* p, long i, bool f32) {
  return f32 ? ((const float*)p)[i] : bf2f(((const unsigned short*)p)[i]);
}
__device__ __forceinline__ void gl_lds16(void* lds_base, const void* g) {
  __builtin_amdgcn_global_load_lds(
      (const __attribute__((address_space(1))) unsigned int*)g,
      (__attribute__((address_space(3))) unsigned int*)lds_base,
      16, 0, 0);
}

__device__ __forceinline__ bool jx_is_i64(const int* jx32) { return jx32[N_ - 1] == 0; }
__device__ __forceinline__ int seg_id(const int* jx32, int n, bool i64) {
  return i64 ? jx32[2 * n] : jx32[n];
}

// Per-block dtype classify (true = x is f32); see round-2 notes.
__device__ __forceinline__ bool classify_f32(const unsigned short* x, int* cnt) {
  int c = 0;
#pragma unroll
  for (int i = 0; i < 8; i++) {
    unsigned short w = x[threadIdx.x * 8 + i];
    int e = (w >> 7) & 0xFF;
    if (e == 0 || (e >= 100 && e <= 140)) c++;
  }
  cnt[threadIdx.x] = c;
  __syncthreads();
  for (int s = 128; s > 0; s >>= 1) {
    if ((int)threadIdx.x < s) cnt[threadIdx.x] += cnt[threadIdx.x + s];
    __syncthreads();
  }
  bool f32 = cnt[0] < 1843;
  __syncthreads();
  return f32;
}

// ---------------------------------------------------------------------------
// prep_all (slim): [0,3078) weights/biases; [3078,3081) seg bounds + flag.
__global__ __launch_bounds__(256)
void prep_all(const void* __restrict__ x, const int* __restrict__ jx,
              const void* __restrict__ Wf, const void* __restrict__ bfv,
              const void* __restrict__ Wg, const void* __restrict__ bgv,
              const void* __restrict__ Wh, const void* __restrict__ bhv,
              unsigned short* __restrict__ Wfg, unsigned short* __restrict__ biasfg,
              unsigned short* __restrict__ Whb, unsigned short* __restrict__ bhb,
              int* __restrict__ segst, int* __restrict__ flag) {
  const int blk = blockIdx.x, tid = threadIdx.x;
  __shared__ int cnt[256];
  const bool f32 = classify_f32((const unsigned short*)x, cnt);
  if (blk >= 3078) {  // bounds + flag
    if (blk == 3078 && tid == 0) flag[0] = f32 ? 1 : 0;
    int s = (blk - 3078) * 256 + tid;
    if (s > S_) return;
    bool i64 = jx_is_i64(jx);
    int lo = 0, hi = N_;
    while (lo < hi) {
      int mid = (lo + hi) >> 1;
      if (seg_id(jx, mid, i64) < s) lo = mid + 1; else hi = mid;
    }
    segst[s] = lo;
    return;
  }
  int idx = blk * 256 + tid;
  if (idx < 524288) {
    int e = idx >> 9, d = idx & 511;
    float v = (e < 512) ? ldf(Wf, (long)e * 512 + d, f32)
                        : ldf(Wg, (long)(e - 512) * 512 + d, f32);
    Wfg[idx] = f2bf(v);
  } else if (idx < 786432) {
    Whb[idx - 524288] = f2bf(ldf(Wh, idx - 524288, f32));
  } else if (idx < 787456) {
    int j = idx - 786432;
    biasfg[j] = f2bf(j < 512 ? ldf(bfv, j, f32) : ldf(bgv, j - 512, f32));
  } else if (idx < 787968) {
    bhb[idx - 787456] = f2bf(ldf(bhv, idx - 787456, f32));
  }
}

// ---------------------------------------------------------------------------
// fg GEMM, R7: R0's proven 2-phase 128x128/BK=32 structure + two fixes:
//  (a) T2 XOR-swizzled LDS: 16B slot s' = k16 ^ (row&3). Kills the 8-way
//      ds_read_b128 conflict of 64B-row tiles (R2: 8.4M conflict-cycles).
//      gl_lds keeps LINEAR dest; inverse swizzle folded into per-lane
//      GLOBAL source offset (rule #21, lane-constant swz_s).
//  (b) T14 async A-stage for f32 x: loads for tile t+1 issued after
//      barrier-2 (fly under MFMA, drain at next barrier-1); cvt+b128
//      write after barrier-1. Same drain points as gl_lds = latency hidden.
// A read directly from x (f32 via (b); bf16 via gl_lds) — no xb round-trip.
#define BK 32

__global__ __launch_bounds__(256, 2)
void gemm_fg(const void* __restrict__ X, const int* __restrict__ flag,
             const unsigned short* __restrict__ Bm,
             const unsigned short* __restrict__ bias,
             unsigned short* __restrict__ Cf, unsigned short* __restrict__ Cg) {
  __shared__ __align__(16) unsigned short As[128 * BK];
  __shared__ __align__(16) unsigned short Bs[128 * BK];
  const bool xf32 = flag[0] != 0;
  const int L = blockIdx.x;
  const int xcd = L & 7, local = L >> 3;
  const int tm = xcd * 64 + local / 8;     // tilesM=512 -> 64 per XCD
  const int tn = local % 8;
  const int m0 = tm * 128, n0 = tn * 128;

  const int tid  = threadIdx.x;
  const int w    = tid >> 6;
  const int lane = tid & 63;
  const int wm   = w >> 1, wn = w & 1;
  const int l15  = lane & 15, l4 = lane >> 4;
  const int srow = lane >> 2;                         // staging row-in-16
  // swizzled lane constants (elements):
  const int swz_s = (((lane & 3) ^ ((lane >> 2) & 3)) << 3);  // stage slot
  const int swz_r = ((l4 ^ (l15 & 3)) << 3);                  // frag read

  f32x4 acc[4][4];
#pragma unroll
  for (int i = 0; i < 4; i++)
#pragma unroll
    for (int j = 0; j < 4; j++) acc[i][j] = (f32x4){0.f, 0.f, 0.f, 0.f};

  const float* xf = (const float*)X;
  const unsigned short* xh = (const unsigned short*)X;
  // f32 A pre-stage registers: rows sr*64 + (tid>>2), cols (tid&3)*8 +{0..7}
  const int prow = tid >> 2;
  const int pk8  = (tid & 3) * 8;
  float4 p0a, p0b, p1a, p1b;
  if (xf32) {  // prologue loads for kt=0
    const float* b0 = xf + (size_t)(m0 + prow) * 512 + pk8;
    const float* b1 = xf + (size_t)(m0 + 64 + prow) * 512 + pk8;
    p0a = *(const float4*)b0; p0b = *(const float4*)(b0 + 4);
    p1a = *(const float4*)b1; p1b = *(const float4*)(b1 + 4);
  }

  for (int kt = 0; kt < 512; kt += BK) {
    __syncthreads();  // drains prev-tile reads AND the in-flight pre-loads
    if (xf32) {
      // cvt + single b128 write per row-half; swizzled slot = swz_s
      bf16x8 v;
      v[0]=f2bf(p0a.x); v[1]=f2bf(p0a.y); v[2]=f2bf(p0a.z); v[3]=f2bf(p0a.w);
      v[4]=f2bf(p0b.x); v[5]=f2bf(p0b.y); v[6]=f2bf(p0b.z); v[7]=f2bf(p0b.w);
      *(bf16x8*)&As[prow * BK + swz_s] = v;
      v[0]=f2bf(p1a.x); v[1]=f2bf(p1a.y); v[2]=f2bf(p1a.z); v[3]=f2bf(p1a.w);
      v[4]=f2bf(p1b.x); v[5]=f2bf(p1b.y); v[6]=f2bf(p1b.z); v[7]=f2bf(p1b.w);
      *(bf16x8*)&As[(64 + prow) * BK + swz_s] = v;
    } else {
#pragma unroll
      for (int r = 0; r < 2; r++) {
        const int rb = (r * 4 + w) * 16;
        gl_lds16(&As[rb * BK], xh + (size_t)(m0 + rb + srow) * 512 + kt + swz_s);
      }
    }
#pragma unroll
    for (int r = 0; r < 2; r++) {
      const int rb = (r * 4 + w) * 16;
      gl_lds16(&Bs[rb * BK], Bm + (size_t)(n0 + rb + srow) * 512 + kt + swz_s);
    }
    __syncthreads();  // gl_lds + ds_writes complete

    if (xf32 && kt + BK < 512) {  // issue t+1 loads; fly under MFMA
      const float* b0 = xf + (size_t)(m0 + prow) * 512 + kt + BK + pk8;
      const float* b1 = xf + (size_t)(m0 + 64 + prow) * 512 + kt + BK + pk8;
      p0a = *(const float4*)b0; p0b = *(const float4*)(b0 + 4);
      p1a = *(const float4*)b1; p1b = *(const float4*)(b1 + 4);
    }

    bf16x8 a[4], bb[4];
#pragma unroll
    for (int i = 0; i < 4; i++)
      a[i] = *(const bf16x8*)&As[(wm * 64 + i * 16 + l15) * BK + swz_r];
#pragma unroll
    for (int j = 0; j < 4; j++)
      bb[j] = *(const bf16x8*)&Bs[(wn * 64 + j * 16 + l15) * BK + swz_r];
#pragma unroll
    for (int i = 0; i < 4; i++)
#pragma unroll
      for (int j = 0; j < 4; j++)
        acc[i][j] = __builtin_amdgcn_mfma_f32_16x16x32_bf16(a[i], bb[j], acc[i][j], 0, 0, 0);
  }

  // epilogue: C/D layout col=lane&15, row=(lane>>4)*4+r; split f (col<512) / g
#pragma unroll
  for (int j = 0; j < 4; j++) {
    const int col = n0 + wn * 64 + j * 16 + l15;
    const float bv = bf2f(bias[col]);
    unsigned short* base = (col < 512) ? Cf : Cg;
    const int cc = col & 511;
#pragma unroll
    for (int i = 0; i < 4; i++) {
      const int rowb = m0 + wm * 64 + i * 16 + l4 * 4;
#pragma unroll
      for (int r = 0; r < 4; r++)
        base[(size_t)(rowb + r) * 512 + cc] = f2bf(acc[i][j][r] + bv);
    }
  }
}

// ---------------------------------------------------------------------------
// Online segment softmax + weighted sum; 2 segments/block, 4 cols/thread,
// n-loop unrolled by 2 for load ILP. |g| < ~7 so no max subtraction.
__global__ __launch_bounds__(256)
void seg_softmax(const unsigned short* __restrict__ f, const unsigned short* __restrict__ g,
                 const int* __restrict__ segst, unsigned short* __restrict__ y) {
  const int s = blockIdx.x * 2 + (threadIdx.x >> 7);
  const int b = blockIdx.y;
  const int d0 = (threadIdx.x & 127) * 4;
  const int st = segst[s], en = segst[s + 1];
  float den0=0.f, den1=0.f, den2=0.f, den3=0.f;
  float y0=0.f, y1=0.f, y2=0.f, y3=0.f;
  int n = st;
  for (; n + 1 < en; n += 2) {
    const size_t offA = (size_t)(b * N_ + n) * 512 + d0;
    const size_t offB = offA + 512;
    const uint2 fpA = *(const uint2*)(f + offA);
    const uint2 gpA = *(const uint2*)(g + offA);
    const uint2 fpB = *(const uint2*)(f + offB);
    const uint2 gpB = *(const uint2*)(g + offB);
    {
      const float f0 = bf2f((unsigned short)fpA.x), f1 = bf2f((unsigned short)(fpA.x >> 16));
      const float f2 = bf2f((unsigned short)fpA.y), f3 = bf2f((unsigned short)(fpA.y >> 16));
      const float g0 = bf2f((unsigned short)gpA.x), g1 = bf2f((unsigned short)(gpA.x >> 16));
      const float g2 = bf2f((unsigned short)gpA.y), g3 = bf2f((unsigned short)(gpA.y >> 16));
      const float e0 = __expf(g0), e1 = __expf(g1), e2 = __expf(g2), e3 = __expf(g3);
      den0 += e0; den1 += e1; den2 += e2; den3 += e3;
      y0 += f0 * e0; y1 += f1 * e1; y2 += f2 * e2; y3 += f3 * e3;
    }
    {
      const float f0 = bf2f((unsigned short)fpB.x), f1 = bf2f((unsigned short)(fpB.x >> 16));
      const float f2 = bf2f((unsigned short)fpB.y), f3 = bf2f((unsigned short)(fpB.y >> 16));
      const float g0 = bf2f((unsigned short)gpB.x), g1 = bf2f((unsigned short)(gpB.x >> 16));
      const float g2 = bf2f((unsigned short)gpB.y), g3 = bf2f((unsigned short)(gpB.y >> 16));
      const float e0 = __expf(g0), e1 = __expf(g1), e2 = __expf(g2), e3 = __expf(g3);
      den0 += e0; den1 += e1; den2 += e2; den3 += e3;
      y0 += f0 * e0; y1 += f1 * e1; y2 += f2 * e2; y3 += f3 * e3;
    }
  }
  if (n < en) {
    const size_t off = (size_t)(b * N_ + n) * 512 + d0;
    const uint2 fp = *(const uint2*)(f + off);
    const uint2 gp = *(const uint2*)(g + off);
    const float f0 = bf2f((unsigned short)fp.x), f1 = bf2f((unsigned short)(fp.x >> 16));
    const float f2 = bf2f((unsigned short)fp.y), f3 = bf2f((unsigned short)(fp.y >> 16));
    const float g0 = bf2f((unsigned short)gp.x), g1 = bf2f((unsigned short)(gp.x >> 16));
    const float g2 = bf2f((unsigned short)gp.y), g3 = bf2f((unsigned short)(gp.y >> 16));
    const float e0 = __expf(g0), e1 = __expf(g1), e2 = __expf(g2), e3 = __expf(g3);
    den0 += e0; den1 += e1; den2 += e2; den3 += e3;
    y0 += f0 * e0; y1 += f1 * e1; y2 += f2 * e2; y3 += f3 * e3;
  }
  uint2 o;
  if (en > st) {
    o.x = (unsigned int)f2bf(y0 / den0) | ((unsigned int)f2bf(y1 / den1) << 16);
    o.y = (unsigned int)f2bf(y2 / den2) | ((unsigned int)f2bf(y3 / den3) << 16);
  } else { o.x = 0u; o.y = 0u; }
  *(uint2*)(y + (size_t)(b * S_ + s) * 512 + d0) = o;
}

// ---------------------------------------------------------------------------
// hy GEMM: hy[m,c] = sum_k y[m,k]*Whb[c,k] + bhb[c]; 64x64 tiles, 256 blocks.
__global__ __launch_bounds__(256)
void gemm_hy(const unsigned short* __restrict__ y, const unsigned short* __restrict__ Whb,
             const unsigned short* __restrict__ bhb, unsigned short* __restrict__ hy) {
  __shared__ __align__(16) unsigned short As[64 * 32];
  __shared__ __align__(16) unsigned short Bs[64 * 32];
  const int tid = threadIdx.x;
  const int w = tid >> 6, lane = tid & 63;
  const int l15 = lane & 15, l4 = lane >> 4;
  const int m0 = (blockIdx.x >> 3) * 64, c0 = (blockIdx.x & 7) * 64;
  const int srow = lane >> 2, scol = (lane & 3) * 8;

  f32x4 acc[4];
#pragma unroll
  for (int j = 0; j < 4; j++) acc[j] = (f32x4){0.f, 0.f, 0.f, 0.f};

  for (int kt = 0; kt < 512; kt += 32) {
    __syncthreads();
    gl_lds16(&As[(w * 16) * 32], y   + (size_t)(m0 + w * 16 + srow) * 512 + kt + scol);
    gl_lds16(&Bs[(w * 16) * 32], Whb + (size_t)(c0 + w * 16 + srow) * 512 + kt + scol);
    __syncthreads();
    bf16x8 a = *(const bf16x8*)&As[(w * 16 + l15) * 32 + l4 * 8];
#pragma unroll
    for (int j = 0; j < 4; j++) {
      bf16x8 bb = *(const bf16x8*)&Bs[(j * 16 + l15) * 32 + l4 * 8];
      acc[j] = __builtin_amdgcn_mfma_f32_16x16x32_bf16(a, bb, acc[j], 0, 0, 0);
    }
  }
#pragma unroll
  for (int j = 0; j < 4; j++) {
    const float bv = bf2f(bhb[c0 + j * 16 + l15]);
#pragma unroll
    for (int r = 0; r < 4; r++)
      hy[(size_t)(m0 + w * 16 + l4 * 4 + r) * 512 + c0 + j * 16 + l15] =
          f2bf(acc[j][r] + bv);
  }
}

// ---------------------------------------------------------------------------
// out[b,n,:] = hy[b*S + jx[n], :]; one wave per row, vectorized stores.
__global__ __launch_bounds__(256)
void gather_out(const unsigned short* __restrict__ hy, const int* __restrict__ jx,
                void* __restrict__ out, const int* __restrict__ flag) {
  const bool f32 = flag[0] != 0;
  const int gid  = blockIdx.x * 256 + threadIdx.x;
  const int wid  = gid >> 6;
  const int lane = gid & 63;
  const int b = wid >> 14;
  const int n = wid & (N_ - 1);
  const bool i64 = jx_is_i64(jx);
  const int s = seg_id(jx, n, i64);
  const bf16x8 v = *(const bf16x8*)(hy + (size_t)(b * S_ + s) * 512 + lane * 8);
  if (f32) {
    float* dst = (float*)out + (size_t)wid * 512 + lane * 8;
    float4 lo, hi;
    lo.x=bf2f((unsigned short)v[0]); lo.y=bf2f((unsigned short)v[1]);
    lo.z=bf2f((unsigned short)v[2]); lo.w=bf2f((unsigned short)v[3]);
    hi.x=bf2f((unsigned short)v[4]); hi.y=bf2f((unsigned short)v[5]);
    hi.z=bf2f((unsigned short)v[6]); hi.w=bf2f((unsigned short)v[7]);
    *(float4*)dst = lo;
    *(float4*)(dst + 4) = hi;
  } else {
    *(bf16x8*)((unsigned short*)out + (size_t)wid * 512 + lane * 8) = v;
  }
}

// ---------------------------------------------------------------------------
extern "C" void kernel_launch(void* const* d_in, const int* in_sizes, int n_in,
                              void* d_out, int out_size, void* d_ws, size_t ws_size,
                              hipStream_t stream) {
  const void* x  = d_in[0];
  const int* jx  = (const int*)d_in[1];
  const void* Wf = d_in[3];
  const void* bf = d_in[4];
  const void* Wg = d_in[5];
  const void* bg = d_in[6];
  const void* Wh = d_in[7];
  const void* bh = d_in[8];

  // EXACT R3-proven ws layout (ends at 72.4 MB; R5 showed 80.8 MB is OOB).
  char* ws = (char*)d_ws;
  int* flag              = (int*)(ws + 0);
  int* segst             = (int*)(ws + 4096);
  unsigned short* biasfg = (unsigned short*)(ws + 8192);
  unsigned short* bhb    = (unsigned short*)(ws + 16384);
  unsigned short* Wfg    = (unsigned short*)(ws + 32768);      // 1 MB
  unsigned short* Whb    = (unsigned short*)(ws + 1081344);    // 0.5 MB
  unsigned short* y_ws   = (unsigned short*)(ws + 1605632);    // 2 MB
  unsigned short* hy_ws  = (unsigned short*)(ws + 3702784);    // 2 MB
  // f/g (2 x 64 MB bf16) live in d_out (128 MB f32); dead before gather.
  unsigned short* fbuf   = (unsigned short*)d_out;
  unsigned short* gbuf   = (unsigned short*)d_out + (size_t)B_ * N_ * D_;

  prep_all<<<3081, 256, 0, stream>>>(x, jx, Wf, bf, Wg, bg, Wh, bh,
                                     Wfg, biasfg, Whb, bhb, segst, flag);
  gemm_fg<<<4096, 256, 0, stream>>>(x, flag, Wfg, biasfg, fbuf, gbuf);
  seg_softmax<<<dim3(256, B_), 256, 0, stream>>>(fbuf, gbuf, segst, y_ws);
  gemm_hy<<<256, 256, 0, stream>>>(y_ws, Whb, bhb, hy_ws);
  gather_out<<<16384, 256, 0, stream>>>(hy_ws, jx, d_out, flag);
}